// Round 9
// baseline (80.898 us; speedup 1.0000x reference)
//
#include <hip/hip_runtime.h>

#define NPTS   4096
#define CFEAT  64
#define RADIUS_F 0.1f

// out layout (floats): grouped_xyz [2,4096,8,3] | grouped_points [2,4096,8,67] | idx [2,4096,8]
#define GX_SZ   (2*NPTS*8*3)       // 196608
#define GP_SZ   (2*NPTS*8*67)      // 4390912

__global__ __launch_bounds__(512) void pointsift_fused_kernel(
    const float* __restrict__ xyz,      // [B,4096,3]
    const float* __restrict__ points,   // [B,4096,64]
    float* __restrict__ out)
{
    __shared__ float4 sxyz4[NPTS];                // 64 KB, 16B/point -> 1 ds_read_b128 per j
    __shared__ unsigned long long best[256];      // [oct][32 pts] 2 KB

    const int t   = threadIdx.x;
    const int bid = blockIdx.x;
    const int b   = bid >> 7;            // batch
    const int base = (bid & 127) * 32;   // first query point of this block

    // ---- stage xyz[b] into padded LDS (8 points/thread; b128 writes conflict-free) ----
    {
        const float* src = xyz + (size_t)b * (NPTS * 3);
        #pragma unroll
        for (int e = 0; e < 8; ++e) {
            const int p = t + 512 * e;
            sxyz4[p] = make_float4(src[p * 3 + 0], src[p * 3 + 1], src[p * 3 + 2], 0.f);
        }
    }
    if (t < 256) best[t] = ~0ull;
    __syncthreads();

    // ---- octant-nearest search, register-blocked: thread = (4 queries, 1 j/iter) ----
    // wave reads 8 CONSECUTIVE j (16B stride -> 32 banks once per 8-lane group, broadcast
    // across query groups); each j tested against 4 register-resident queries.
    const int lane = t & 63;
    const int wv   = t >> 6;             // wave 0..7, owns j-range [wv*512, wv*512+512)
    const int jo   = lane & 7;           // j offset within 8-j group
    const int qg   = lane >> 3;          // query group 0..7
    const int q0   = qg * 4;             // first of this thread's 4 queries

    float qx[4], qy[4], qz[4];
    #pragma unroll
    for (int s = 0; s < 4; ++s) {
        const float4 q = sxyz4[base + q0 + s];
        qx[s] = q.x; qy[s] = q.y; qz[s] = q.z;
    }

    const int jstart = wv * 512 + jo;
    #pragma unroll 2
    for (int it = 0; it < 64; ++it) {
        const int j = jstart + it * 8;
        const float4 pj = sxyz4[j];
        #pragma unroll
        for (int s = 0; s < 4; ++s) {
            const float dx = pj.x - qx[s];
            const float dy = pj.y - qy[s];
            const float dz = pj.z - qz[s];
            if (fmaxf(fabsf(dx), fmaxf(fabsf(dy), fabsf(dz))) < RADIUS_F) {
                // match XLA: separate f32 mul/add, no contraction (argmin tie safety)
                const float dist = __fadd_rn(__fadd_rn(__fmul_rn(dx, dx), __fmul_rn(dy, dy)),
                                             __fmul_rn(dz, dz));
                const int oct = ((dx > 0.f) ? 4 : 0) | ((dy > 0.f) ? 2 : 0) | ((dz > 0.f) ? 1 : 0);
                const unsigned long long key =
                    ((unsigned long long)__float_as_uint(dist) << 32) | (unsigned int)j;
                atomicMin(&best[(oct << 5) | (q0 + s)], key);  // lex (dist, j) min == argmin
            }
        }
    }
    __syncthreads();   // best[] complete; no further LDS writes -> no second barrier needed

    float* gx_out  = out;                 // [B,N,8,3]
    float* gp_out  = out + GX_SZ;         // [B,N,8,67]
    float* idx_out = out + GX_SZ + GP_SZ; // [B,N,8] as float

    // ---- epilogue A (waves 0-3): resolve idx, write idx + grouped_xyz + gp[0:3] ----
    if (t < 256) {
        const int o  = t & 7;            // octant  (coalesced g mapping)
        const int pp = t >> 3;           // local point
        const int ii = base + pp;
        const unsigned long long key = best[(o << 5) | pp];
        const int j = (key == ~0ull) ? ii : (int)(unsigned int)(key & 0xFFFFFFFFull);
        const size_t g = ((size_t)(b * NPTS + ii) << 3) + o;   // (b,i,o) row id
        const float4 pj = sxyz4[j];
        const float4 pi = sxyz4[ii];
        const float gx = pj.x - pi.x;
        const float gy = pj.y - pi.y;
        const float gz = pj.z - pi.z;
        gx_out[g * 3 + 0] = gx;
        gx_out[g * 3 + 1] = gy;
        gx_out[g * 3 + 2] = gz;
        gp_out[g * 67 + 0] = gx;
        gp_out[g * 67 + 1] = gy;
        gp_out[g * 67 + 2] = gz;
        idx_out[g] = (float)j;
    }
    // (no barrier: epilogue B reads only best[], already fenced above; waves 4-7
    //  start the gather while waves 0-3 finish epilogue A)

    // ---- epilogue B: gather features, wave wv handles octant wv ----
    const float* pbase = points + (size_t)b * (NPTS * CFEAT);
    #pragma unroll 4
    for (int q = 0; q < 32; ++q) {
        const unsigned long long key = best[(wv << 5) + q];   // wave-uniform broadcast
        const int ii = base + q;
        const int j = (key == ~0ull) ? ii : (int)(unsigned int)(key & 0xFFFFFFFFull);
        const size_t g = ((size_t)(b * NPTS + ii) << 3) + wv;
        gp_out[g * 67 + 3 + lane] = pbase[(size_t)j * CFEAT + lane];  // coalesced 256B row
    }
}

extern "C" void kernel_launch(void* const* d_in, const int* in_sizes, int n_in,
                              void* d_out, int out_size, void* d_ws, size_t ws_size,
                              hipStream_t stream) {
    const float* xyz    = (const float*)d_in[0];   // [2,4096,3]
    const float* points = (const float*)d_in[1];   // [2,4096,64]
    float* out = (float*)d_out;
    pointsift_fused_kernel<<<256, 512, 0, stream>>>(xyz, points, out);
}

// Round 10
// 79.419 us; speedup vs baseline: 1.0186x; 1.0186x over previous
//
#include <hip/hip_runtime.h>

#define NPTS   4096
#define CFEAT  64
#define RADIUS_F 0.1f

// out layout (floats): grouped_xyz [2,4096,8,3] | grouped_points [2,4096,8,67] | idx [2,4096,8]
#define GX_SZ   (2*NPTS*8*3)       // 196608
#define GP_SZ   (2*NPTS*8*67)      // 4390912

__global__ __launch_bounds__(512) void pointsift_fused_kernel(
    const float* __restrict__ xyz,      // [B,4096,3]
    const float* __restrict__ points,   // [B,4096,64]
    float* __restrict__ out)
{
    __shared__ float sxyz[NPTS * 3];              // 48 KB linear (x y z interleaved)
    __shared__ unsigned long long best[256];      // [oct][32 pts] 2 KB

    const int t   = threadIdx.x;
    const int bid = blockIdx.x;
    const int b   = bid >> 7;            // batch
    const int base = (bid & 127) * 32;   // first query point of this block

    // ---- stage xyz[b] into LDS: 3072 float4 / 512 threads = 6 dwordx4 each (proven fast) ----
    {
        const float4* src = (const float4*)(xyz + (size_t)b * (NPTS * 3));
        float4* dst = (float4*)sxyz;
        #pragma unroll
        for (int e = 0; e < 6; ++e) dst[t + 512 * e] = src[t + 512 * e];
    }
    if (t < 256) best[t] = ~0ull;
    __syncthreads();

    // ---- octant-nearest search: thread = (4 queries x 4 consecutive j)/iter ----
    // 4 consecutive j (j0%4==0) = 48B = 3 aligned float4 -> 3 ds_read_b128 per 4 j.
    // Lanes jo=0..7 read byte jo*48+{0,16,32}: bank-quads cover all 32 banks once,
    // broadcast across the 8 query groups -> conflict-free.
    const int lane = t & 63;
    const int wv   = t >> 6;             // wave 0..7, owns j-range [wv*512, wv*512+512)
    const int jo   = lane & 7;           // j-group offset within wave's 32-j slab
    const int qg   = lane >> 3;          // query group 0..7
    const int q0   = qg * 4;             // first of this thread's 4 queries

    float qx[4], qy[4], qz[4];
    #pragma unroll
    for (int s = 0; s < 4; ++s) {
        const int i = base + q0 + s;
        qx[s] = sxyz[i * 3 + 0];
        qy[s] = sxyz[i * 3 + 1];
        qz[s] = sxyz[i * 3 + 2];
    }

    const int jg0 = wv * 512 + jo * 4;
    for (int it = 0; it < 16; ++it) {
        const int jg = jg0 + it * 32;            // first of 4 consecutive j
        const float4 va = *(const float4*)&sxyz[jg * 3 + 0];  // x0 y0 z0 x1
        const float4 vb = *(const float4*)&sxyz[jg * 3 + 4];  // y1 z1 x2 y2
        const float4 vc = *(const float4*)&sxyz[jg * 3 + 8];  // z2 x3 y3 z3
        const float px[4] = {va.x, va.w, vb.z, vc.y};
        const float py[4] = {va.y, vb.x, vb.w, vc.z};
        const float pz[4] = {va.z, vb.y, vc.x, vc.w};
        #pragma unroll
        for (int m = 0; m < 4; ++m) {
            #pragma unroll
            for (int s = 0; s < 4; ++s) {
                const float dx = px[m] - qx[s];
                const float dy = py[m] - qy[s];
                const float dz = pz[m] - qz[s];
                if (fmaxf(fabsf(dx), fmaxf(fabsf(dy), fabsf(dz))) < RADIUS_F) {
                    // match XLA: separate f32 mul/add, no contraction (argmin tie safety)
                    const float dist = __fadd_rn(__fadd_rn(__fmul_rn(dx, dx), __fmul_rn(dy, dy)),
                                                 __fmul_rn(dz, dz));
                    const int oct = ((dx > 0.f) ? 4 : 0) | ((dy > 0.f) ? 2 : 0) | ((dz > 0.f) ? 1 : 0);
                    const unsigned long long key =
                        ((unsigned long long)__float_as_uint(dist) << 32) | (unsigned int)(jg + m);
                    atomicMin(&best[(oct << 5) | (q0 + s)], key);  // lex (dist,j) min == argmin
                }
            }
        }
    }
    __syncthreads();   // best[] complete; no LDS writes after this point

    float* gx_out  = out;                 // [B,N,8,3]
    float* gp_out  = out + GX_SZ;         // [B,N,8,67]
    float* idx_out = out + GX_SZ + GP_SZ; // [B,N,8] as float

    // ---- epilogue A (waves 0-3): resolve idx, write idx + grouped_xyz + gp[0:3] ----
    if (t < 256) {
        const int o  = t & 7;            // octant  (coalesced g mapping)
        const int pp = t >> 3;           // local point
        const int ii = base + pp;
        const unsigned long long key = best[(o << 5) | pp];
        const int j = (key == ~0ull) ? ii : (int)(unsigned int)(key & 0xFFFFFFFFull);
        const size_t g = ((size_t)(b * NPTS + ii) << 3) + o;   // (b,i,o) row id
        const float gx = sxyz[j * 3 + 0] - sxyz[ii * 3 + 0];
        const float gy = sxyz[j * 3 + 1] - sxyz[ii * 3 + 1];
        const float gz = sxyz[j * 3 + 2] - sxyz[ii * 3 + 2];
        gx_out[g * 3 + 0] = gx;
        gx_out[g * 3 + 1] = gy;
        gx_out[g * 3 + 2] = gz;
        gp_out[g * 67 + 0] = gx;
        gp_out[g * 67 + 1] = gy;
        gp_out[g * 67 + 2] = gz;
        idx_out[g] = (float)j;
    }
    // (no barrier: epilogue B reads only best[], fenced above; waves 4-7 start
    //  the gather while waves 0-3 finish epilogue A)

    // ---- epilogue B: gather features, wave wv handles octant wv ----
    const float* pbase = points + (size_t)b * (NPTS * CFEAT);
    #pragma unroll 4
    for (int q = 0; q < 32; ++q) {
        const unsigned long long key = best[(wv << 5) + q];   // wave-uniform broadcast
        const int ii = base + q;
        const int j = (key == ~0ull) ? ii : (int)(unsigned int)(key & 0xFFFFFFFFull);
        const size_t g = ((size_t)(b * NPTS + ii) << 3) + wv;
        gp_out[g * 67 + 3 + lane] = pbase[(size_t)j * CFEAT + lane];  // coalesced 256B row
    }
}

extern "C" void kernel_launch(void* const* d_in, const int* in_sizes, int n_in,
                              void* d_out, int out_size, void* d_ws, size_t ws_size,
                              hipStream_t stream) {
    const float* xyz    = (const float*)d_in[0];   // [2,4096,3]
    const float* points = (const float*)d_in[1];   // [2,4096,64]
    float* out = (float*)d_out;
    pointsift_fused_kernel<<<256, 512, 0, stream>>>(xyz, points, out);
}